// Round 7
// baseline (178.912 us; speedup 1.0000x reference)
//
#include <hip/hip_runtime.h>
#include <hip/hip_bf16.h>
#include <math.h>

typedef __attribute__((ext_vector_type(8))) short short8v;
typedef __attribute__((ext_vector_type(4))) float f32x4;

#define NB 64
#define CC 64
#define TT 300
#define VV 25
#define SS 3
#define TB 4
#define TBLK (TT/TB)   // 75

// ws layout:
//   floats [n*128 + o]        per-n channel sum    (n<64, o<64)
//   floats [n*128 + 64 + o]   per-n channel sumsq          -> [0 .. 8192) floats
//   floats [8192+o] scale, [8256+o] shift
//   byte 36864: A-hat frags  [s][nt][lane] 16B   (6144 B)
//   byte 49152: Wc bf16 frags [s][ot][kt][lane]  (24576 B)
//   byte 131072: unnormalized-y bf16 buffer      (61.44 MB)
#define AFA_BYTES 36864
#define WCF_BYTES 49152
#define YOFF_BYTES 131072

static __device__ __forceinline__ unsigned short f2bf(float f){
    union { __hip_bfloat16 h; unsigned short s; } u;
    u.h = __float2bfloat16(f);
    return u.s;
}
static __device__ __forceinline__ float bf2f(unsigned short b){
    return __uint_as_float(((unsigned)b) << 16);
}
static __device__ __forceinline__ void pack2(const f32x4& z, unsigned& d0, unsigned& d1){
    d0 = (unsigned)f2bf(z[0]) | ((unsigned)f2bf(z[1]) << 16);
    d1 = (unsigned)f2bf(z[2]) | ((unsigned)f2bf(z[3]) << 16);
}
static __device__ __forceinline__ short8v mk8(unsigned q0,unsigned q1,unsigned q2,unsigned q3){
    union { unsigned u[4]; short8v v; } x;
    x.u[0]=q0; x.u[1]=q1; x.u[2]=q2; x.u[3]=q3;
    return x.v;
}

__global__ void gcn_prep(const float* __restrict__ PA, const float* __restrict__ Wc,
                         float* __restrict__ ws)
{
    __shared__ float inv[SS][VV];
    const int tid = threadIdx.x;   // 384 threads
    for (int i = tid; i < 8192; i += 384) ws[i] = 0.f;   // zero per-n partials
    if (tid < SS*VV){
        int s = tid/VV, w = tid%VV;
        float sum = 0.f;
        for (int v=0; v<VV; ++v){ float p = PA[s*VV*VV + v*VV + w]; sum = fmaf(p,p,sum); }
        inv[s][w] = 1.f/(sqrtf(sum)+1e-4f);
    }
    __syncthreads();
    {   // A-hat fragments (stage-A B operand), zeros for v>=25 / w>=25
        int s = tid/128, rem = tid%128, nt = rem/64, lane = rem%64;
        int w = nt*16 + (lane&15), g = lane>>4;
        short8v vals;
        #pragma unroll
        for (int j=0;j<8;++j){
            int v = 8*g + j;
            float f = (v<VV && w<VV) ? PA[s*VV*VV + v*VV + w]*inv[s][w] : 0.f;
            vals[j] = (short)f2bf(f);
        }
        *(short8v*)((char*)ws + AFA_BYTES + (size_t)((s*2+nt)*64 + lane)*16) = vals;
    }
    // Wc fragments (stage-B A operand): fid = ((s*4+ot)*2+kt)*64+lane
    for (int fid = tid; fid < SS*4*2*64; fid += 384){
        int lane = fid & 63;
        int kt = (fid >> 6) & 1;
        int ot = (fid >> 7) & 3;
        int s  = fid >> 9;
        int o  = 16*ot + (lane & 15);
        int c0 = kt*32 + 8*(lane >> 4);
        short8v vals;
        #pragma unroll
        for (int j=0;j<8;++j) vals[j] = (short)f2bf(Wc[((size_t)s*CC + o)*CC + c0 + j]);
        *(short8v*)((char*)ws + WCF_BYTES + (size_t)fid*16) = vals;
    }
}

#define XPITCH 36   // shorts per row; 72 B -> b64-aligned, ~2-way max conflicts

template<bool YB>
__global__ __launch_bounds__(256,8) void gcn_main_kernel(
    const float* __restrict__ x, float* __restrict__ ws,
    float* __restrict__ yf32, __hip_bfloat16* __restrict__ ybf)
{
    // 18432 B: phase 1 = x tile [t*64+c][v] bf16; phase 2 (reuse) = y tile [o][t*25+w]
    __shared__ __align__(16) unsigned short lds[256*XPITCH];

    const int tid  = threadIdx.x;
    const int lane = tid & 63;
    const int wv   = tid >> 6;                 // wave owns t = t0 + wv
    const int l15  = lane & 15, g = lane >> 4;
    const int n    = blockIdx.x / TBLK;
    const int t0   = (blockIdx.x % TBLK) * TB;
    const int t    = t0 + wv;

    // zero junk v-columns 25..31 for every row (stage-A K padding)
    #pragma unroll
    for (int k = 25; k < 32; ++k) lds[tid*XPITCH + k] = 0;

    // ---- coalesced staging: x[n, :, t0:t0+4, :] -> lds[(tloc*64+c)][v] bf16 ----
    const float4* x4 = (const float4*)(x + ((size_t)n*CC*TT + t0)*VV);
    for (int i4 = tid; i4 < CC*TB*VV/4; i4 += 256){   // 1600 float4
        int c = i4 / (TB*VV/4);
        int j = i4 % (TB*VV/4);
        float4 v4 = x4[c*(TT*VV/4) + j];
        float vals[4] = {v4.x, v4.y, v4.z, v4.w};
        int e = 4*j;
        #pragma unroll
        for (int k=0;k<4;++k){
            int ee = e+k;
            lds[((ee/VV)*64 + c)*XPITCH + (ee%VV)] = f2bf(vals[k]);
        }
    }
    __syncthreads();

    // stage-A x fragments from LDS: rows c = 16mt+l15 (fixed t), k-octet v = 8g..8g+7
    short8v axf[4];
    #pragma unroll
    for (int mt=0; mt<4; ++mt){
        const unsigned short* rp = &lds[(wv*64 + 16*mt + l15)*XPITCH + 8*g];
        uint2 lo = *(const uint2*)rp;        // v = 8g..8g+3
        uint2 hi = *(const uint2*)(rp + 4);  // v = 8g+4..8g+7
        axf[mt] = mk8(lo.x, lo.y, hi.x, hi.y);
    }

    const short8v* afrag = (const short8v*)((const char*)ws + AFA_BYTES);
    const short8v* wfrag = (const short8v*)((const char*)ws + WCF_BYTES);

    const f32x4 zf = {0.f,0.f,0.f,0.f};
    f32x4 yacc[4][2];
    #pragma unroll
    for (int ot=0; ot<4; ++ot){ yacc[ot][0]=zf; yacc[ot][1]=zf; }

    const int sLo = 32*(g&1) + l15;
    const int sHi = sLo + 16;
    const bool hi = (lane >= 32);

    #pragma unroll 1
    for (int s=0; s<SS; ++s){
        short8v aA0 = afrag[(s*2+0)*64 + lane];
        short8v aA1 = afrag[(s*2+1)*64 + lane];
        #pragma unroll
        for (int kt=0; kt<2; ++kt){
            // stage A: Z rows c in [kt*32, kt*32+32)
            f32x4 z00 = __builtin_amdgcn_mfma_f32_16x16x32_bf16(axf[2*kt+0], aA0, zf, 0,0,0);
            f32x4 z01 = __builtin_amdgcn_mfma_f32_16x16x32_bf16(axf[2*kt+0], aA1, zf, 0,0,0);
            f32x4 z10 = __builtin_amdgcn_mfma_f32_16x16x32_bf16(axf[2*kt+1], aA0, zf, 0,0,0);
            f32x4 z11 = __builtin_amdgcn_mfma_f32_16x16x32_bf16(axf[2*kt+1], aA1, zf, 0,0,0);
            unsigned pLo0n0, pLo1n0, pLo0n1, pLo1n1;   // mt = 2kt
            unsigned pHi0n0, pHi1n0, pHi0n1, pHi1n1;   // mt = 2kt+1
            pack2(z00, pLo0n0, pLo1n0);
            pack2(z01, pLo0n1, pLo1n1);
            pack2(z10, pHi0n0, pHi1n0);
            pack2(z11, pHi0n1, pHi1n1);
            // in-register transpose -> stage-B B-fragments (k = c octets)
            unsigned a0,b0,a1,b1,a2,b2,a3,b3;
            a0=__shfl(pLo0n0,sLo); b0=__shfl(pHi0n0,sLo);
            a1=__shfl(pLo1n0,sLo); b1=__shfl(pHi1n0,sLo);
            a2=__shfl(pLo0n0,sHi); b2=__shfl(pHi0n0,sHi);
            a3=__shfl(pLo1n0,sHi); b3=__shfl(pHi1n0,sHi);
            short8v bz0 = mk8(hi?b0:a0, hi?b1:a1, hi?b2:a2, hi?b3:a3);
            a0=__shfl(pLo0n1,sLo); b0=__shfl(pHi0n1,sLo);
            a1=__shfl(pLo1n1,sLo); b1=__shfl(pHi1n1,sLo);
            a2=__shfl(pLo0n1,sHi); b2=__shfl(pHi0n1,sHi);
            a3=__shfl(pLo1n1,sHi); b3=__shfl(pHi1n1,sHi);
            short8v bz1 = mk8(hi?b0:a0, hi?b1:a1, hi?b2:a2, hi?b3:a3);
            // stage B: 4 o-tiles x 2 nt, this kt
            #pragma unroll
            for (int ot=0; ot<4; ++ot){
                short8v wc = wfrag[((s*4+ot)*2+kt)*64 + lane];
                yacc[ot][0] = __builtin_amdgcn_mfma_f32_16x16x32_bf16(wc, bz0, yacc[ot][0], 0,0,0);
                yacc[ot][1] = __builtin_amdgcn_mfma_f32_16x16x32_bf16(wc, bz1, yacc[ot][1], 0,0,0);
            }
        }
    }

    __syncthreads();   // x tile fully consumed (axf live in regs) — reuse LDS for y
    // store unnormalized y (conv bias cancels through training-mode BN — omitted),
    // and mirror into LDS [o][t_loc*25+w] bf16 for block-level stats
    #pragma unroll
    for (int ot=0; ot<4; ++ot){
        #pragma unroll
        for (int r=0; r<4; ++r){
            const int o = 16*ot + 4*g + r;
            const size_t base = (size_t)(n*CC + o)*(TT*VV) + (size_t)t*VV;
            unsigned short b0 = f2bf(yacc[ot][0][r]);
            lds[o*100 + wv*25 + l15] = b0;
            if (YB) ybf[base + l15] = __float2bfloat16(yacc[ot][0][r]);
            else    yf32[base + l15] = yacc[ot][0][r];
            if (l15 < VV-16){
                unsigned short b1 = f2bf(yacc[ot][1][r]);
                lds[o*100 + wv*25 + 16 + l15] = b1;
                if (YB) ybf[base + 16 + l15] = __float2bfloat16(yacc[ot][1][r]);
                else    yf32[base + 16 + l15] = yacc[ot][1][r];
            }
        }
    }
    __syncthreads();

    // block-level stats: thread (o = tid>>2, q = tid&3) sums 25 values
    {
        const int o = tid >> 2, q = tid & 3;
        float s1 = 0.f, s2 = 0.f;
        #pragma unroll
        for (int k=0; k<VV; ++k){
            float v = bf2f(lds[o*100 + q*25 + k]);
            s1 += v;
            s2 = fmaf(v, v, s2);
        }
        s1 += __shfl_xor(s1,1); s1 += __shfl_xor(s1,2);
        s2 += __shfl_xor(s2,1); s2 += __shfl_xor(s2,2);
        if (q == 0){
            atomicAdd(&ws[n*128 + o],      s1);
            atomicAdd(&ws[n*128 + 64 + o], s2);
        }
    }
}

__global__ void gcn_finalize_kernel(const float* __restrict__ gamma,
                                    const float* __restrict__ beta,
                                    float* __restrict__ ws)
{
    const int o = threadIdx.x;
    if (o < CC) {
        float s = 0.f, q = 0.f;
        for (int n = 0; n < NB; ++n){
            s += ws[n*128 + o];
            q += ws[n*128 + 64 + o];
        }
        const float cnt = (float)(NB * TT * VV);   // 480000
        const float mean = s / cnt;
        const float var  = q / cnt - mean * mean;
        const float sc   = gamma[o] * rsqrtf(var + 1e-5f);
        ws[8192 + o] = sc;
        ws[8256 + o] = beta[o] - mean * sc;
    }
}

template<bool YB>
__global__ __launch_bounds__(256) void gcn_bn_relu_kernel(
    const float* __restrict__ x, float* __restrict__ out,
    const float* __restrict__ ws, const unsigned short* __restrict__ ybf)
{
    const int total4 = NB * CC * TT * VV / 4;   // 7,680,000
    const int per_c4 = TT * VV / 4;             // 1875
    for (int i = blockIdx.x * 256 + threadIdx.x; i < total4; i += gridDim.x * 256) {
        const int c = (i / per_c4) & (CC - 1);
        const float sc = ws[8192 + c];
        const float sh = ws[8256 + c];
        float4 yv;
        if (YB){
            uint2 yb = *(const uint2*)&ybf[4*i];
            yv.x = bf2f((unsigned short)(yb.x & 0xffff));
            yv.y = bf2f((unsigned short)(yb.x >> 16));
            yv.z = bf2f((unsigned short)(yb.y & 0xffff));
            yv.w = bf2f((unsigned short)(yb.y >> 16));
        } else {
            yv = reinterpret_cast<float4*>(out)[i];
        }
        float4 xv = reinterpret_cast<const float4*>(x)[i];
        float4 r;
        r.x = fmaxf(fmaf(yv.x, sc, sh) + xv.x, 0.f);
        r.y = fmaxf(fmaf(yv.y, sc, sh) + xv.y, 0.f);
        r.z = fmaxf(fmaf(yv.z, sc, sh) + xv.z, 0.f);
        r.w = fmaxf(fmaf(yv.w, sc, sh) + xv.w, 0.f);
        reinterpret_cast<float4*>(out)[i] = r;
    }
}

extern "C" void kernel_launch(void* const* d_in, const int* in_sizes, int n_in,
                              void* d_out, int out_size, void* d_ws, size_t ws_size,
                              hipStream_t stream)
{
    const float* x     = (const float*)d_in[0];
    const float* PA    = (const float*)d_in[1];
    const float* Wc    = (const float*)d_in[2];
    const float* gamma = (const float*)d_in[4];
    const float* beta  = (const float*)d_in[5];
    float* out = (float*)d_out;
    float* ws  = (float*)d_ws;

    const size_t ybytes = (size_t)NB*CC*TT*VV*2;
    const bool yb = ws_size >= (size_t)YOFF_BYTES + ybytes;
    __hip_bfloat16* ybf = (__hip_bfloat16*)((char*)d_ws + YOFF_BYTES);

    gcn_prep<<<1, 384, 0, stream>>>(PA, Wc, ws);
    if (yb){
        gcn_main_kernel<true><<<NB*TBLK, 256, 0, stream>>>(x, ws, out, ybf);
        gcn_finalize_kernel<<<1, 64, 0, stream>>>(gamma, beta, ws);
        gcn_bn_relu_kernel<true><<<2048, 256, 0, stream>>>(x, out, ws, (const unsigned short*)ybf);
    } else {
        gcn_main_kernel<false><<<NB*TBLK, 256, 0, stream>>>(x, ws, out, ybf);
        gcn_finalize_kernel<<<1, 64, 0, stream>>>(gamma, beta, ws);
        gcn_bn_relu_kernel<false><<<2048, 256, 0, stream>>>(x, out, ws, (const unsigned short*)ybf);
    }
}

// Round 8
// 140.782 us; speedup vs baseline: 1.2708x; 1.2708x over previous
//
#include <hip/hip_runtime.h>
#include <hip/hip_bf16.h>
#include <math.h>

typedef __attribute__((ext_vector_type(8))) short short8v;
typedef __attribute__((ext_vector_type(4))) float f32x4;

#define NB 64
#define CC 64
#define TT 300
#define VV 25
#define SS 3
#define TB 4
#define TBLK (TT/TB)   // 75

// ws layout:
//   floats [n*128 + o]        per-n channel sum    (n<64, o<64)
//   floats [n*128 + 64 + o]   per-n channel sumsq          -> [0 .. 8192) floats
//   floats [8192+o] scale, [8256+o] shift
//   byte 36864: A-hat frags  [s][nt][lane] 16B   (6144 B)
//   byte 49152: Wc bf16 frags [s][ot][kt][lane]  (24576 B)
//   byte 131072: unnormalized-y bf16 buffer      (61.44 MB)
#define AFA_BYTES 36864
#define WCF_BYTES 49152
#define YOFF_BYTES 131072

static __device__ __forceinline__ unsigned short f2bf(float f){
    union { __hip_bfloat16 h; unsigned short s; } u;
    u.h = __float2bfloat16(f);
    return u.s;
}
static __device__ __forceinline__ float bf2f(unsigned short b){
    return __uint_as_float(((unsigned)b) << 16);
}
static __device__ __forceinline__ void pack2(const f32x4& z, unsigned& d0, unsigned& d1){
    d0 = (unsigned)f2bf(z[0]) | ((unsigned)f2bf(z[1]) << 16);
    d1 = (unsigned)f2bf(z[2]) | ((unsigned)f2bf(z[3]) << 16);
}
static __device__ __forceinline__ short8v mk8(unsigned q0,unsigned q1,unsigned q2,unsigned q3){
    union { unsigned u[4]; short8v v; } x;
    x.u[0]=q0; x.u[1]=q1; x.u[2]=q2; x.u[3]=q3;
    return x.v;
}

__global__ void gcn_prep(const float* __restrict__ PA, const float* __restrict__ Wc,
                         float* __restrict__ ws)
{
    __shared__ float inv[SS][VV];
    const int tid = threadIdx.x;   // 384 threads
    for (int i = tid; i < 8192; i += 384) ws[i] = 0.f;   // zero per-n partials
    if (tid < SS*VV){
        int s = tid/VV, w = tid%VV;
        float sum = 0.f;
        for (int v=0; v<VV; ++v){ float p = PA[s*VV*VV + v*VV + w]; sum = fmaf(p,p,sum); }
        inv[s][w] = 1.f/(sqrtf(sum)+1e-4f);
    }
    __syncthreads();
    {   // A-hat fragments (stage-A B operand), zeros for v>=25 / w>=25
        int s = tid/128, rem = tid%128, nt = rem/64, lane = rem%64;
        int w = nt*16 + (lane&15), g = lane>>4;
        short8v vals;
        #pragma unroll
        for (int j=0;j<8;++j){
            int v = 8*g + j;
            float f = (v<VV && w<VV) ? PA[s*VV*VV + v*VV + w]*inv[s][w] : 0.f;
            vals[j] = (short)f2bf(f);
        }
        *(short8v*)((char*)ws + AFA_BYTES + (size_t)((s*2+nt)*64 + lane)*16) = vals;
    }
    // Wc fragments (stage-B A operand): fid = ((s*4+ot)*2+kt)*64+lane
    for (int fid = tid; fid < SS*4*2*64; fid += 384){
        int lane = fid & 63;
        int kt = (fid >> 6) & 1;
        int ot = (fid >> 7) & 3;
        int s  = fid >> 9;
        int o  = 16*ot + (lane & 15);
        int c0 = kt*32 + 8*(lane >> 4);
        short8v vals;
        #pragma unroll
        for (int j=0;j<8;++j) vals[j] = (short)f2bf(Wc[((size_t)s*CC + o)*CC + c0 + j]);
        *(short8v*)((char*)ws + WCF_BYTES + (size_t)fid*16) = vals;
    }
}

#define XPITCH 36   // shorts per row; 72 B -> b64-aligned, ~4-way worst conflicts

template<bool YB>
__global__ __launch_bounds__(256,6) void gcn_main_kernel(
    const float* __restrict__ x, float* __restrict__ ws,
    float* __restrict__ yf32, __hip_bfloat16* __restrict__ ybf)
{
    // 18432 B: phase 1 = x tile [t*64+c][v] bf16; phase 2 (reuse) = y tile [o][t*25+w]
    __shared__ __align__(16) unsigned short lds[256*XPITCH];

    const int tid  = threadIdx.x;
    const int lane = tid & 63;
    const int wv   = tid >> 6;                 // wave owns t = t0 + wv
    const int l15  = lane & 15, g = lane >> 4;
    const int n    = blockIdx.x / TBLK;
    const int t0   = (blockIdx.x % TBLK) * TB;
    const int t    = t0 + wv;

    // zero junk v-columns 25..31 for every row (stage-A K padding), packed stores
    lds[tid*XPITCH + 25] = 0;
    *(unsigned*)&lds[tid*XPITCH + 26] = 0u;
    *(uint2*)&lds[tid*XPITCH + 28] = make_uint2(0u,0u);

    // ---- coalesced staging: x[n, :, t0:t0+4, :] -> lds[(tloc*64+c)][v] bf16 ----
    const float4* x4 = (const float4*)(x + ((size_t)n*CC*TT + t0)*VV);
    for (int i4 = tid; i4 < CC*TB*VV/4; i4 += 256){   // 1600 float4
        int c = i4 / (TB*VV/4);
        int j = i4 % (TB*VV/4);
        float4 v4 = x4[c*(TT*VV/4) + j];
        float vals[4] = {v4.x, v4.y, v4.z, v4.w};
        int e = 4*j;
        #pragma unroll
        for (int k=0;k<4;++k){
            int ee = e+k;
            lds[((ee/VV)*64 + c)*XPITCH + (ee%VV)] = f2bf(vals[k]);
        }
    }
    __syncthreads();

    // stage-A x fragments from LDS: rows c = 16mt+l15 (fixed t), k-octet v = 8g..8g+7
    short8v axf[4];
    #pragma unroll
    for (int mt=0; mt<4; ++mt){
        const unsigned short* rp = &lds[(wv*64 + 16*mt + l15)*XPITCH + 8*g];
        uint2 lo = *(const uint2*)rp;        // v = 8g..8g+3
        uint2 hi = *(const uint2*)(rp + 4);  // v = 8g+4..8g+7
        axf[mt] = mk8(lo.x, lo.y, hi.x, hi.y);
    }

    const short8v* afrag = (const short8v*)((const char*)ws + AFA_BYTES);
    const short8v* wfrag = (const short8v*)((const char*)ws + WCF_BYTES);

    const f32x4 zf = {0.f,0.f,0.f,0.f};
    f32x4 yacc[4][2];
    #pragma unroll
    for (int ot=0; ot<4; ++ot){ yacc[ot][0]=zf; yacc[ot][1]=zf; }

    const int sLo = 32*(g&1) + l15;
    const int sHi = sLo + 16;
    const bool hi = (lane >= 32);

    #pragma unroll 1
    for (int s=0; s<SS; ++s){
        short8v aA0 = afrag[(s*2+0)*64 + lane];
        short8v aA1 = afrag[(s*2+1)*64 + lane];
        #pragma unroll
        for (int kt=0; kt<2; ++kt){
            // stage A: Z rows c in [kt*32, kt*32+32)
            f32x4 z00 = __builtin_amdgcn_mfma_f32_16x16x32_bf16(axf[2*kt+0], aA0, zf, 0,0,0);
            f32x4 z01 = __builtin_amdgcn_mfma_f32_16x16x32_bf16(axf[2*kt+0], aA1, zf, 0,0,0);
            f32x4 z10 = __builtin_amdgcn_mfma_f32_16x16x32_bf16(axf[2*kt+1], aA0, zf, 0,0,0);
            f32x4 z11 = __builtin_amdgcn_mfma_f32_16x16x32_bf16(axf[2*kt+1], aA1, zf, 0,0,0);
            unsigned pLo0n0, pLo1n0, pLo0n1, pLo1n1;   // mt = 2kt
            unsigned pHi0n0, pHi1n0, pHi0n1, pHi1n1;   // mt = 2kt+1
            pack2(z00, pLo0n0, pLo1n0);
            pack2(z01, pLo0n1, pLo1n1);
            pack2(z10, pHi0n0, pHi1n0);
            pack2(z11, pHi0n1, pHi1n1);
            // in-register transpose -> stage-B B-fragments (k = c octets)
            unsigned a0,b0,a1,b1,a2,b2,a3,b3;
            a0=__shfl(pLo0n0,sLo); b0=__shfl(pHi0n0,sLo);
            a1=__shfl(pLo1n0,sLo); b1=__shfl(pHi1n0,sLo);
            a2=__shfl(pLo0n0,sHi); b2=__shfl(pHi0n0,sHi);
            a3=__shfl(pLo1n0,sHi); b3=__shfl(pHi1n0,sHi);
            short8v bz0 = mk8(hi?b0:a0, hi?b1:a1, hi?b2:a2, hi?b3:a3);
            a0=__shfl(pLo0n1,sLo); b0=__shfl(pHi0n1,sLo);
            a1=__shfl(pLo1n1,sLo); b1=__shfl(pHi1n1,sLo);
            a2=__shfl(pLo0n1,sHi); b2=__shfl(pHi0n1,sHi);
            a3=__shfl(pLo1n1,sHi); b3=__shfl(pHi1n1,sHi);
            short8v bz1 = mk8(hi?b0:a0, hi?b1:a1, hi?b2:a2, hi?b3:a3);
            // stage B: 4 o-tiles x 2 nt, this kt
            #pragma unroll
            for (int ot=0; ot<4; ++ot){
                short8v wc = wfrag[((s*4+ot)*2+kt)*64 + lane];
                yacc[ot][0] = __builtin_amdgcn_mfma_f32_16x16x32_bf16(wc, bz0, yacc[ot][0], 0,0,0);
                yacc[ot][1] = __builtin_amdgcn_mfma_f32_16x16x32_bf16(wc, bz1, yacc[ot][1], 0,0,0);
            }
        }
    }

    __syncthreads();   // x tile fully consumed (axf live in regs) — reuse LDS for y
    // store unnormalized y (conv bias cancels through training-mode BN — omitted),
    // and mirror into LDS [o][t_loc*25+w] bf16 for block-level stats
    #pragma unroll
    for (int ot=0; ot<4; ++ot){
        #pragma unroll
        for (int r=0; r<4; ++r){
            const int o = 16*ot + 4*g + r;
            const size_t base = (size_t)(n*CC + o)*(TT*VV) + (size_t)t*VV;
            unsigned short b0 = f2bf(yacc[ot][0][r]);
            lds[o*100 + wv*25 + l15] = b0;
            if (YB) ybf[base + l15] = __float2bfloat16(yacc[ot][0][r]);
            else    yf32[base + l15] = yacc[ot][0][r];
            if (l15 < VV-16){
                unsigned short b1 = f2bf(yacc[ot][1][r]);
                lds[o*100 + wv*25 + 16 + l15] = b1;
                if (YB) ybf[base + 16 + l15] = __float2bfloat16(yacc[ot][1][r]);
                else    yf32[base + 16 + l15] = yacc[ot][1][r];
            }
        }
    }
    __syncthreads();

    // block-level stats: thread (o = tid>>2, q = tid&3) sums 25 values
    {
        const int o = tid >> 2, q = tid & 3;
        float s1 = 0.f, s2 = 0.f;
        #pragma unroll
        for (int k=0; k<VV; ++k){
            float v = bf2f(lds[o*100 + q*25 + k]);
            s1 += v;
            s2 = fmaf(v, v, s2);
        }
        s1 += __shfl_xor(s1,1); s1 += __shfl_xor(s1,2);
        s2 += __shfl_xor(s2,1); s2 += __shfl_xor(s2,2);
        if (q == 0){
            atomicAdd(&ws[n*128 + o],      s1);
            atomicAdd(&ws[n*128 + 64 + o], s2);
        }
    }
}

__global__ void gcn_finalize_kernel(const float* __restrict__ gamma,
                                    const float* __restrict__ beta,
                                    float* __restrict__ ws)
{
    const int o = threadIdx.x;
    if (o < CC) {
        float s = 0.f, q = 0.f;
        for (int n = 0; n < NB; ++n){
            s += ws[n*128 + o];
            q += ws[n*128 + 64 + o];
        }
        const float cnt = (float)(NB * TT * VV);   // 480000
        const float mean = s / cnt;
        const float var  = q / cnt - mean * mean;
        const float sc   = gamma[o] * rsqrtf(var + 1e-5f);
        ws[8192 + o] = sc;
        ws[8256 + o] = beta[o] - mean * sc;
    }
}

template<bool YB>
__global__ __launch_bounds__(256) void gcn_bn_relu_kernel(
    const float* __restrict__ x, float* __restrict__ out,
    const float* __restrict__ ws, const unsigned short* __restrict__ ybf)
{
    const int total4 = NB * CC * TT * VV / 4;   // 7,680,000
    const int per_c4 = TT * VV / 4;             // 1875
    for (int i = blockIdx.x * 256 + threadIdx.x; i < total4; i += gridDim.x * 256) {
        const int c = (i / per_c4) & (CC - 1);
        const float sc = ws[8192 + c];
        const float sh = ws[8256 + c];
        float4 yv;
        if (YB){
            uint2 yb = *(const uint2*)&ybf[4*i];
            yv.x = bf2f((unsigned short)(yb.x & 0xffff));
            yv.y = bf2f((unsigned short)(yb.x >> 16));
            yv.z = bf2f((unsigned short)(yb.y & 0xffff));
            yv.w = bf2f((unsigned short)(yb.y >> 16));
        } else {
            yv = reinterpret_cast<float4*>(out)[i];
        }
        float4 xv = reinterpret_cast<const float4*>(x)[i];
        float4 r;
        r.x = fmaxf(fmaf(yv.x, sc, sh) + xv.x, 0.f);
        r.y = fmaxf(fmaf(yv.y, sc, sh) + xv.y, 0.f);
        r.z = fmaxf(fmaf(yv.z, sc, sh) + xv.z, 0.f);
        r.w = fmaxf(fmaf(yv.w, sc, sh) + xv.w, 0.f);
        reinterpret_cast<float4*>(out)[i] = r;
    }
}

extern "C" void kernel_launch(void* const* d_in, const int* in_sizes, int n_in,
                              void* d_out, int out_size, void* d_ws, size_t ws_size,
                              hipStream_t stream)
{
    const float* x     = (const float*)d_in[0];
    const float* PA    = (const float*)d_in[1];
    const float* Wc    = (const float*)d_in[2];
    const float* gamma = (const float*)d_in[4];
    const float* beta  = (const float*)d_in[5];
    float* out = (float*)d_out;
    float* ws  = (float*)d_ws;

    const size_t ybytes = (size_t)NB*CC*TT*VV*2;
    const bool yb = ws_size >= (size_t)YOFF_BYTES + ybytes;
    __hip_bfloat16* ybf = (__hip_bfloat16*)((char*)d_ws + YOFF_BYTES);

    gcn_prep<<<1, 384, 0, stream>>>(PA, Wc, ws);
    if (yb){
        gcn_main_kernel<true><<<NB*TBLK, 256, 0, stream>>>(x, ws, out, ybf);
        gcn_finalize_kernel<<<1, 64, 0, stream>>>(gamma, beta, ws);
        gcn_bn_relu_kernel<true><<<2048, 256, 0, stream>>>(x, out, ws, (const unsigned short*)ybf);
    } else {
        gcn_main_kernel<false><<<NB*TBLK, 256, 0, stream>>>(x, ws, out, ybf);
        gcn_finalize_kernel<<<1, 64, 0, stream>>>(gamma, beta, ws);
        gcn_bn_relu_kernel<false><<<2048, 256, 0, stream>>>(x, out, ws, (const unsigned short*)ybf);
    }
}

// Round 9
// 131.764 us; speedup vs baseline: 1.3578x; 1.0684x over previous
//
#include <hip/hip_runtime.h>
#include <hip/hip_bf16.h>
#include <math.h>

typedef __attribute__((ext_vector_type(8))) short short8v;
typedef __attribute__((ext_vector_type(4))) float f32x4;

#define NB 64
#define CC 64
#define TT 300
#define VV 25
#define SS 3
#define TB 4
#define TBLK (TT/TB)   // 75

// ws layout:
//   floats [n*128 + o]        per-n channel sum    (n<64, o<64)
//   floats [n*128 + 64 + o]   per-n channel sumsq          -> [0 .. 8192) floats
//   floats [8192+o] scale, [8256+o] shift
//   byte 36864: A-hat frags  [s][nt][lane] 16B   (6144 B)
//   byte 49152: Wc bf16 frags [s][ot][kt][lane]  (24576 B)
//   byte 131072: unnormalized-y bf16 buffer      (61.44 MB)
#define AFA_BYTES 36864
#define WCF_BYTES 49152
#define YOFF_BYTES 131072

static __device__ __forceinline__ unsigned short f2bf(float f){
    union { __hip_bfloat16 h; unsigned short s; } u;
    u.h = __float2bfloat16(f);
    return u.s;
}
static __device__ __forceinline__ float bf2f(unsigned short b){
    return __uint_as_float(((unsigned)b) << 16);
}
static __device__ __forceinline__ void pack2(const f32x4& z, unsigned& d0, unsigned& d1){
    d0 = (unsigned)f2bf(z[0]) | ((unsigned)f2bf(z[1]) << 16);
    d1 = (unsigned)f2bf(z[2]) | ((unsigned)f2bf(z[3]) << 16);
}
static __device__ __forceinline__ short8v mk8(unsigned q0,unsigned q1,unsigned q2,unsigned q3){
    union { unsigned u[4]; short8v v; } x;
    x.u[0]=q0; x.u[1]=q1; x.u[2]=q2; x.u[3]=q3;
    return x.v;
}

__global__ void gcn_prep(const float* __restrict__ PA, const float* __restrict__ Wc,
                         float* __restrict__ ws)
{
    __shared__ float inv[SS][VV];
    const int tid = threadIdx.x;   // 384 threads
    for (int i = tid; i < 8192; i += 384) ws[i] = 0.f;   // zero per-n partials
    if (tid < SS*VV){
        int s = tid/VV, w = tid%VV;
        float sum = 0.f;
        for (int v=0; v<VV; ++v){ float p = PA[s*VV*VV + v*VV + w]; sum = fmaf(p,p,sum); }
        inv[s][w] = 1.f/(sqrtf(sum)+1e-4f);
    }
    __syncthreads();
    {   // A-hat fragments (stage-A B operand), zeros for v>=25 / w>=25
        int s = tid/128, rem = tid%128, nt = rem/64, lane = rem%64;
        int w = nt*16 + (lane&15), g = lane>>4;
        short8v vals;
        #pragma unroll
        for (int j=0;j<8;++j){
            int v = 8*g + j;
            float f = (v<VV && w<VV) ? PA[s*VV*VV + v*VV + w]*inv[s][w] : 0.f;
            vals[j] = (short)f2bf(f);
        }
        *(short8v*)((char*)ws + AFA_BYTES + (size_t)((s*2+nt)*64 + lane)*16) = vals;
    }
    // Wc fragments (stage-B A operand): fid = ((s*4+ot)*2+kt)*64+lane
    for (int fid = tid; fid < SS*4*2*64; fid += 384){
        int lane = fid & 63;
        int kt = (fid >> 6) & 1;
        int ot = (fid >> 7) & 3;
        int s  = fid >> 9;
        int o  = 16*ot + (lane & 15);
        int c0 = kt*32 + 8*(lane >> 4);
        short8v vals;
        #pragma unroll
        for (int j=0;j<8;++j) vals[j] = (short)f2bf(Wc[((size_t)s*CC + o)*CC + c0 + j]);
        *(short8v*)((char*)ws + WCF_BYTES + (size_t)fid*16) = vals;
    }
}

#define XPITCH 36   // shorts per row; 72 B -> b64-aligned

template<bool YB>
__global__ __launch_bounds__(256,6) void gcn_main_kernel(
    const float* __restrict__ x, float* __restrict__ ws,
    float* __restrict__ yf32, __hip_bfloat16* __restrict__ ybf)
{
    // 18432 B: phase 1 = x tile [t*64+c][v] bf16; phase 2 (reuse) = y tile [o][t*25+w]
    __shared__ __align__(16) unsigned short lds[256*XPITCH];

    const int tid  = threadIdx.x;
    const int lane = tid & 63;
    const int wv   = tid >> 6;                 // wave owns t = t0 + wv
    const int l15  = lane & 15, g = lane >> 4;
    const int n    = blockIdx.x / TBLK;
    const int t0   = (blockIdx.x % TBLK) * TB;

    // zero junk v-columns 25..31 for every row (stage-A K padding), packed stores
    lds[tid*XPITCH + 25] = 0;
    *(unsigned*)&lds[tid*XPITCH + 26] = 0u;
    *(uint2*)&lds[tid*XPITCH + 28] = make_uint2(0u,0u);

    // ---- coalesced staging: x[n, :, t0:t0+4, :] -> lds[(tloc*64+c)][v] bf16 ----
    const float4* x4 = (const float4*)(x + ((size_t)n*CC*TT + t0)*VV);
    for (int i4 = tid; i4 < CC*TB*VV/4; i4 += 256){   // 1600 float4
        int c = i4 / (TB*VV/4);
        int j = i4 % (TB*VV/4);
        float4 v4 = x4[c*(TT*VV/4) + j];
        float vals[4] = {v4.x, v4.y, v4.z, v4.w};
        int e = 4*j;
        #pragma unroll
        for (int k=0;k<4;++k){
            int ee = e+k;
            lds[((ee/VV)*64 + c)*XPITCH + (ee%VV)] = f2bf(vals[k]);
        }
    }
    __syncthreads();

    // stage-A x fragments from LDS: rows c = 16mt+l15 (fixed t), k-octet v = 8g..8g+7
    short8v axf[4];
    #pragma unroll
    for (int mt=0; mt<4; ++mt){
        const unsigned short* rp = &lds[(wv*64 + 16*mt + l15)*XPITCH + 8*g];
        uint2 lo = *(const uint2*)rp;        // v = 8g..8g+3
        uint2 hi = *(const uint2*)(rp + 4);  // v = 8g+4..8g+7
        axf[mt] = mk8(lo.x, lo.y, hi.x, hi.y);
    }

    const short8v* afrag = (const short8v*)((const char*)ws + AFA_BYTES);
    const short8v* wfrag = (const short8v*)((const char*)ws + WCF_BYTES);

    const f32x4 zf = {0.f,0.f,0.f,0.f};
    f32x4 yacc[4][2];
    #pragma unroll
    for (int ot=0; ot<4; ++ot){ yacc[ot][0]=zf; yacc[ot][1]=zf; }

    const int sLo = 32*(g&1) + l15;
    const int sHi = sLo + 16;
    const bool hi = (lane >= 32);

    #pragma unroll 1
    for (int s=0; s<SS; ++s){
        short8v aA0 = afrag[(s*2+0)*64 + lane];
        short8v aA1 = afrag[(s*2+1)*64 + lane];
        #pragma unroll
        for (int kt=0; kt<2; ++kt){
            // stage A: Z rows c in [kt*32, kt*32+32)
            f32x4 z00 = __builtin_amdgcn_mfma_f32_16x16x32_bf16(axf[2*kt+0], aA0, zf, 0,0,0);
            f32x4 z01 = __builtin_amdgcn_mfma_f32_16x16x32_bf16(axf[2*kt+0], aA1, zf, 0,0,0);
            f32x4 z10 = __builtin_amdgcn_mfma_f32_16x16x32_bf16(axf[2*kt+1], aA0, zf, 0,0,0);
            f32x4 z11 = __builtin_amdgcn_mfma_f32_16x16x32_bf16(axf[2*kt+1], aA1, zf, 0,0,0);
            unsigned pLo0n0, pLo1n0, pLo0n1, pLo1n1;   // mt = 2kt
            unsigned pHi0n0, pHi1n0, pHi0n1, pHi1n1;   // mt = 2kt+1
            pack2(z00, pLo0n0, pLo1n0);
            pack2(z01, pLo0n1, pLo1n1);
            pack2(z10, pHi0n0, pHi1n0);
            pack2(z11, pHi0n1, pHi1n1);
            // in-register transpose -> stage-B B-fragments (k = c octets)
            unsigned a0,b0,a1,b1,a2,b2,a3,b3;
            a0=__shfl(pLo0n0,sLo); b0=__shfl(pHi0n0,sLo);
            a1=__shfl(pLo1n0,sLo); b1=__shfl(pHi1n0,sLo);
            a2=__shfl(pLo0n0,sHi); b2=__shfl(pHi0n0,sHi);
            a3=__shfl(pLo1n0,sHi); b3=__shfl(pHi1n0,sHi);
            short8v bz0 = mk8(hi?b0:a0, hi?b1:a1, hi?b2:a2, hi?b3:a3);
            a0=__shfl(pLo0n1,sLo); b0=__shfl(pHi0n1,sLo);
            a1=__shfl(pLo1n1,sLo); b1=__shfl(pHi1n1,sLo);
            a2=__shfl(pLo0n1,sHi); b2=__shfl(pHi0n1,sHi);
            a3=__shfl(pLo1n1,sHi); b3=__shfl(pHi1n1,sHi);
            short8v bz1 = mk8(hi?b0:a0, hi?b1:a1, hi?b2:a2, hi?b3:a3);
            // stage B: 4 o-tiles x 2 nt, this kt
            #pragma unroll
            for (int ot=0; ot<4; ++ot){
                short8v wc = wfrag[((s*4+ot)*2+kt)*64 + lane];
                yacc[ot][0] = __builtin_amdgcn_mfma_f32_16x16x32_bf16(wc, bz0, yacc[ot][0], 0,0,0);
                yacc[ot][1] = __builtin_amdgcn_mfma_f32_16x16x32_bf16(wc, bz1, yacc[ot][1], 0,0,0);
            }
        }
    }

    __syncthreads();   // x tile fully consumed (axf live in regs) — reuse LDS for y
    // write y ONLY into LDS tile [o][t_loc*25+w] bf16 (no scattered global stores)
    #pragma unroll
    for (int ot=0; ot<4; ++ot){
        #pragma unroll
        for (int r=0; r<4; ++r){
            const int o = 16*ot + 4*g + r;
            lds[o*100 + wv*25 + l15] = f2bf(yacc[ot][0][r]);
            if (l15 < VV-16)
                lds[o*100 + wv*25 + 16 + l15] = f2bf(yacc[ot][1][r]);
        }
    }
    __syncthreads();

    // coalesced global store of the y tile: 64 rows x 200 B, thread-linear uint2
    // (conv bias cancels through training-mode BN — omitted)
    for (int i = tid; i < 1600; i += 256){
        const int row = i / 25;          // o
        const int c8  = i % 25;          // 4-short group within the 100 cols
        uint2 d = *(const uint2*)&lds[row*100 + c8*4];
        const size_t base = (size_t)(n*CC + row)*(TT*VV) + (size_t)t0*VV + c8*4;
        if (YB){
            *(uint2*)((unsigned short*)ybf + base) = d;
        } else {
            float4 f;
            f.x = bf2f((unsigned short)(d.x & 0xffff));
            f.y = bf2f((unsigned short)(d.x >> 16));
            f.z = bf2f((unsigned short)(d.y & 0xffff));
            f.w = bf2f((unsigned short)(d.y >> 16));
            *(float4*)(yf32 + base) = f;
        }
    }

    // block-level stats: thread (o = tid>>2, q = tid&3) sums 25 values
    {
        const int o = tid >> 2, q = tid & 3;
        float s1 = 0.f, s2 = 0.f;
        #pragma unroll
        for (int k=0; k<VV; ++k){
            float v = bf2f(lds[o*100 + q*25 + k]);
            s1 += v;
            s2 = fmaf(v, v, s2);
        }
        s1 += __shfl_xor(s1,1); s1 += __shfl_xor(s1,2);
        s2 += __shfl_xor(s2,1); s2 += __shfl_xor(s2,2);
        if (q == 0){
            atomicAdd(&ws[n*128 + o],      s1);
            atomicAdd(&ws[n*128 + 64 + o], s2);
        }
    }
}

__global__ void gcn_finalize_kernel(const float* __restrict__ gamma,
                                    const float* __restrict__ beta,
                                    float* __restrict__ ws)
{
    const int o = threadIdx.x;
    if (o < CC) {
        float s = 0.f, q = 0.f;
        for (int n = 0; n < NB; ++n){
            s += ws[n*128 + o];
            q += ws[n*128 + 64 + o];
        }
        const float cnt = (float)(NB * TT * VV);   // 480000
        const float mean = s / cnt;
        const float var  = q / cnt - mean * mean;
        const float sc   = gamma[o] * rsqrtf(var + 1e-5f);
        ws[8192 + o] = sc;
        ws[8256 + o] = beta[o] - mean * sc;
    }
}

template<bool YB>
__global__ __launch_bounds__(256) void gcn_bn_relu_kernel(
    const float* __restrict__ x, float* __restrict__ out,
    const float* __restrict__ ws, const unsigned short* __restrict__ ybf)
{
    const int total4 = NB * CC * TT * VV / 4;   // 7,680,000
    const int per_c4 = TT * VV / 4;             // 1875
    for (int i = blockIdx.x * 256 + threadIdx.x; i < total4; i += gridDim.x * 256) {
        const int c = (i / per_c4) & (CC - 1);
        const float sc = ws[8192 + c];
        const float sh = ws[8256 + c];
        float4 yv;
        if (YB){
            uint2 yb = *(const uint2*)&ybf[4*i];
            yv.x = bf2f((unsigned short)(yb.x & 0xffff));
            yv.y = bf2f((unsigned short)(yb.x >> 16));
            yv.z = bf2f((unsigned short)(yb.y & 0xffff));
            yv.w = bf2f((unsigned short)(yb.y >> 16));
        } else {
            yv = reinterpret_cast<float4*>(out)[i];
        }
        float4 xv = reinterpret_cast<const float4*>(x)[i];
        float4 r;
        r.x = fmaxf(fmaf(yv.x, sc, sh) + xv.x, 0.f);
        r.y = fmaxf(fmaf(yv.y, sc, sh) + xv.y, 0.f);
        r.z = fmaxf(fmaf(yv.z, sc, sh) + xv.z, 0.f);
        r.w = fmaxf(fmaf(yv.w, sc, sh) + xv.w, 0.f);
        reinterpret_cast<float4*>(out)[i] = r;
    }
}

extern "C" void kernel_launch(void* const* d_in, const int* in_sizes, int n_in,
                              void* d_out, int out_size, void* d_ws, size_t ws_size,
                              hipStream_t stream)
{
    const float* x     = (const float*)d_in[0];
    const float* PA    = (const float*)d_in[1];
    const float* Wc    = (const float*)d_in[2];
    const float* gamma = (const float*)d_in[4];
    const float* beta  = (const float*)d_in[5];
    float* out = (float*)d_out;
    float* ws  = (float*)d_ws;

    const size_t ybytes = (size_t)NB*CC*TT*VV*2;
    const bool yb = ws_size >= (size_t)YOFF_BYTES + ybytes;
    __hip_bfloat16* ybf = (__hip_bfloat16*)((char*)d_ws + YOFF_BYTES);

    gcn_prep<<<1, 384, 0, stream>>>(PA, Wc, ws);
    if (yb){
        gcn_main_kernel<true><<<NB*TBLK, 256, 0, stream>>>(x, ws, out, ybf);
        gcn_finalize_kernel<<<1, 64, 0, stream>>>(gamma, beta, ws);
        gcn_bn_relu_kernel<true><<<2048, 256, 0, stream>>>(x, out, ws, (const unsigned short*)ybf);
    } else {
        gcn_main_kernel<false><<<NB*TBLK, 256, 0, stream>>>(x, ws, out, ybf);
        gcn_finalize_kernel<<<1, 64, 0, stream>>>(gamma, beta, ws);
        gcn_bn_relu_kernel<false><<<2048, 256, 0, stream>>>(x, out, ws, (const unsigned short*)ybf);
    }
}